// Round 21
// baseline (303.735 us; speedup 1.0000x reference)
//
#include <hip/hip_runtime.h>
#include <hip/hip_bf16.h>

#define HDIM 256
#define IDIM 512
#define NST 16
#define KCONV 4
#define LAYERS 4
#define BATCH 4
#define LSEQ 1024
#define TOK (BATCH * LSEQ)   // 4096

typedef unsigned short u16;
typedef float f32x4 __attribute__((ext_vector_type(4)));
typedef short bf16x8 __attribute__((ext_vector_type(8)));

static __device__ __forceinline__ u16 f2bf(float f) {
    __hip_bfloat16 h = __float2bfloat16(f);
    return reinterpret_cast<u16&>(h);
}
static __device__ __forceinline__ float bf2f(u16 b) {
    return __builtin_bit_cast(float, (unsigned)b << 16);
}
// unpack bf16 #j (j=0..3) from a uint2 holding 4 packed bf16 (j compile-time)
static __device__ __forceinline__ float bfup(uint2 u, int j) {
    unsigned w = (j < 2) ? u.x : u.y;
    unsigned bits = (j & 1) ? (w & 0xffff0000u) : (w << 16);
    return __builtin_bit_cast(float, bits);
}

// DPP butterfly add over each 16-lane row (all lanes end with the row sum).
#define DPP_ROW_ADD(p, CTRL)                                                   \
    p += __builtin_bit_cast(float, __builtin_amdgcn_update_dpp(                \
             0, __builtin_bit_cast(int, p), CTRL, 0xf, 0xf, false))

// -------------------- embedding --------------------
__global__ __launch_bounds__(256) void embed_kernel(const int* __restrict__ ids,
                                                    const float* __restrict__ embed,
                                                    float* __restrict__ h) {
    int idx = blockIdx.x * 256 + threadIdx.x;
    if (idx < TOK * HDIM) {
        int tok = idx >> 8;
        int c = idx & (HDIM - 1);
        h[idx] = embed[ids[tok] * HDIM + c];
    }
}

// -------------------- f32 -> bf16 bulk convert, 4 weight arrays in one launch ------
__global__ __launch_bounds__(256) void cvt4_bf16_kernel(const float* __restrict__ s0, u16* __restrict__ d0,
                                                        const float* __restrict__ s1, u16* __restrict__ d1,
                                                        const float* __restrict__ s2, u16* __restrict__ d2,
                                                        const float* __restrict__ s3, u16* __restrict__ d3) {
    const float* in;
    u16* out;
    int base;
    int bid = blockIdx.x;
    if (bid < 1024)      { in = s0; out = d0; base = bid; }
    else if (bid < 1536) { in = s1; out = d1; base = bid - 1024; }
    else if (bid < 1632) { in = s2; out = d2; base = bid - 1536; }
    else                 { in = s3; out = d3; base = bid - 1632; }
    int j = (base * 256 + threadIdx.x) * 4;
    float4 v = *(const float4*)&in[j];
    unsigned lo = (unsigned)f2bf(v.x) | ((unsigned)f2bf(v.y) << 16);
    unsigned hi = (unsigned)f2bf(v.z) | ((unsigned)f2bf(v.w) << 16);
    *(uint2*)&out[j] = make_uint2(lo, hi);
}

// -------------------- rmsnorm (layer 0 only): one wave per token ----------------
__global__ __launch_bounds__(256) void rmsnorm_kernel(const float* __restrict__ h,
                                                      const float* __restrict__ w,
                                                      u16* __restrict__ xb) {
    int wid = threadIdx.x >> 6, lane = threadIdx.x & 63;
    int tok = blockIdx.x * 4 + wid;
    float4 v = *(const float4*)&h[(size_t)tok * HDIM + lane * 4];
    float s = v.x * v.x + v.y * v.y + v.z * v.z + v.w * v.w;
    #pragma unroll
    for (int m = 32; m >= 1; m >>= 1) s += __shfl_xor(s, m, 64);
    float rstd = rsqrtf(s * (1.0f / HDIM) + 1e-5f);
    float4 wv = *(const float4*)&w[lane * 4];
    unsigned lo = (unsigned)f2bf(v.x * rstd * wv.x) | ((unsigned)f2bf(v.y * rstd * wv.y) << 16);
    unsigned hi = (unsigned)f2bf(v.z * rstd * wv.z) | ((unsigned)f2bf(v.w * rstd * wv.w) << 16);
    *(uint2*)&xb[(size_t)tok * HDIM + lane * 4] = make_uint2(lo, hi);
}

// -------------------- bf16 MFMA GEMM 128x128 (in_proj): C = A @ W^T, bf16 out ----
__global__ __launch_bounds__(256) void gemm_bf16_kernel(const u16* __restrict__ A,
                                                        const u16* __restrict__ W,
                                                        u16* __restrict__ C,
                                                        int M, int N, int K) {
    const int BM = 128, BK = 32;
    __shared__ __align__(16) u16 Al[BM][BK + 8];
    __shared__ __align__(16) u16 Bl[BM][BK + 8];
    int m0 = blockIdx.y * BM, n0 = blockIdx.x * BM;
    int tid = threadIdx.x;
    int lane = tid & 63;
    int wid = tid >> 6;
    int wr = wid >> 1, wc = wid & 1;
    int r = lane & 15, g = lane >> 4;

    f32x4 acc[4][4] = {};

    int srow = tid & 127;
    const u16* src = (tid < 128) ? (A + (size_t)(m0 + srow) * K)
                                 : (W + (size_t)(n0 + srow) * K);
    u16* dstrow = (tid < 128) ? &Al[srow][0] : &Bl[srow][0];

    for (int k0 = 0; k0 < K; k0 += BK) {
        uint4 v0 = *(const uint4*)(src + k0);
        uint4 v1 = *(const uint4*)(src + k0 + 8);
        uint4 v2 = *(const uint4*)(src + k0 + 16);
        uint4 v3 = *(const uint4*)(src + k0 + 24);
        __syncthreads();
        *(uint4*)(dstrow)      = v0;
        *(uint4*)(dstrow + 8)  = v1;
        *(uint4*)(dstrow + 16) = v2;
        *(uint4*)(dstrow + 24) = v3;
        __syncthreads();

        bf16x8 af[4], bfr[4];
        #pragma unroll
        for (int f = 0; f < 4; ++f) {
            af[f]  = *(const bf16x8*)&Al[wr * 64 + f * 16 + r][g * 8];
            bfr[f] = *(const bf16x8*)&Bl[wc * 64 + f * 16 + r][g * 8];
        }
        #pragma unroll
        for (int fm = 0; fm < 4; ++fm)
            #pragma unroll
            for (int fn = 0; fn < 4; ++fn)
                acc[fm][fn] = __builtin_amdgcn_mfma_f32_16x16x32_bf16(
                    af[fm], bfr[fn], acc[fm][fn], 0, 0, 0);
    }

    #pragma unroll
    for (int fm = 0; fm < 4; ++fm) {
        #pragma unroll
        for (int fn = 0; fn < 4; ++fn) {
            int col = n0 + wc * 64 + fn * 16 + r;
            #pragma unroll
            for (int v = 0; v < 4; ++v) {
                int row = m0 + wr * 64 + fm * 16 + g * 4 + v;
                C[(size_t)row * N + col] = f2bf(acc[fm][fn][v]);
            }
        }
    }
}

// -------------------- out_proj + residual + next-layer rmsnorm fused --------------
// 512 threads: 8 waves, wave w owns cols [w*32, w*32+32) (2 n-frags), K=512
// streamed from L2. rmsnorm epilogue on threads 0..255.
__global__ __launch_bounds__(512) void outproj_norm_kernel(const u16* __restrict__ Y,   // yb [TOK][512]
                                                           const u16* __restrict__ W,   // wob [256][512]
                                                           const float* __restrict__ nw,// next norm_w [256]
                                                           float* __restrict__ h,
                                                           u16* __restrict__ xb) {
    __shared__ float sH[16][260];
    int m0 = blockIdx.x * 16;
    int tid = threadIdx.x;
    int lane = tid & 63;
    int w = tid >> 6;                  // 0..7
    int r = lane & 15, g = lane >> 4;

    f32x4 acc[2] = {};
    const u16* yrow  = Y + (size_t)(m0 + r) * 512 + g * 8;
    const u16* wbase = W + (size_t)(w * 32 + r) * 512 + g * 8;
    #pragma unroll
    for (int k0 = 0; k0 < 512; k0 += 32) {
        bf16x8 af = *(const bf16x8*)(yrow + k0);
        #pragma unroll
        for (int fn = 0; fn < 2; ++fn) {
            bf16x8 bfr = *(const bf16x8*)(wbase + (size_t)fn * 16 * 512 + k0);
            acc[fn] = __builtin_amdgcn_mfma_f32_16x16x32_bf16(af, bfr, acc[fn], 0, 0, 0);
        }
    }

    #pragma unroll
    for (int fn = 0; fn < 2; ++fn) {
        int col = w * 32 + fn * 16 + r;
        #pragma unroll
        for (int v = 0; v < 4; ++v) {
            int row = g * 4 + v;
            size_t off = (size_t)(m0 + row) * HDIM + col;
            float hv = h[off] + acc[fn][v];
            h[off] = hv;
            sH[row][col] = hv;
        }
    }
    __syncthreads();

    if (tid < 256) {
        int row = tid >> 4, part = tid & 15;
        const float* sr = &sH[row][part * 16];
        float s = 0.f;
        #pragma unroll
        for (int j = 0; j < 16; ++j) s = fmaf(sr[j], sr[j], s);
        DPP_ROW_ADD(s, 0xB1);
        DPP_ROW_ADD(s, 0x4E);
        DPP_ROW_ADD(s, 0x141);
        DPP_ROW_ADD(s, 0x140);
        float rstd = rsqrtf(s * (1.0f / HDIM) + 1e-5f);
        const float* nwp = &nw[part * 16];
        unsigned pk[8];
        #pragma unroll
        for (int j = 0; j < 8; ++j) {
            u16 lo = f2bf(sr[2 * j]     * rstd * nwp[2 * j]);
            u16 hi = f2bf(sr[2 * j + 1] * rstd * nwp[2 * j + 1]);
            pk[j] = (unsigned)lo | ((unsigned)hi << 16);
        }
        u16* dst = xb + (size_t)(m0 + row) * HDIM + part * 16;
        *(uint4*)(dst)     = make_uint4(pk[0], pk[1], pk[2], pk[3]);
        *(uint4*)(dst + 8) = make_uint4(pk[4], pk[5], pk[6], pk[7]);
    }
}

// -------------------- conv + x_proj + dt_proj fused --------------------
// xs_T now emitted as f32 (scan reads it unpacked); gate_T stays bf16.
__global__ __launch_bounds__(512) void xproj_kernel(const u16* __restrict__ proj,  // [TOK][1024]
                                                    const float* __restrict__ cw,
                                                    const float* __restrict__ cb,
                                                    const u16* __restrict__ W,     // xwb [48][512]
                                                    const u16* __restrict__ dtw,   // [512][16]
                                                    const float* __restrict__ dtb, // [512]
                                                    float* __restrict__ bc,
                                                    float* __restrict__ dtT,
                                                    float* __restrict__ xs_T,
                                                    u16* __restrict__ gate_T) {
    __shared__ __align__(16) u16 xsL[16][520];
    __shared__ float sP[8][16][52];
    __shared__ float sT[16][52];
    int m0 = blockIdx.x * 16;
    int tid = threadIdx.x;
    int lane = tid & 63;
    int w = tid >> 6;                  // wave id
    int r = lane & 15, g = lane >> 4;
    int tl = m0 & (LSEQ - 1);          // seq-local base (block-uniform)

    // ---- conv + silu, channel ic = tid ----
    {
        int ic = tid;
        const u16* pxs = proj + (size_t)m0 * 1024 + ic;
        float4 wq = *(const float4*)&cw[ic * 4];
        float bias = cb[ic];
        float a0 = (tl >= 3) ? bf2f(pxs[-3 * 1024]) : 0.f;
        float a1 = (tl >= 2) ? bf2f(pxs[-2 * 1024]) : 0.f;
        float a2 = (tl >= 1) ? bf2f(pxs[-1 * 1024]) : 0.f;
        float xf[16];
        unsigned gr[8];
        #pragma unroll
        for (int t = 0; t < 16; ++t) {
            float a3 = bf2f(pxs[t * 1024]);
            float acc = bias;
            acc = fmaf(a0, wq.x, acc);
            acc = fmaf(a1, wq.y, acc);
            acc = fmaf(a2, wq.z, acc);
            acc = fmaf(a3, wq.w, acc);
            float xsv = acc / (1.f + __expf(-acc));
            xsL[t][ic] = f2bf(xsv);
            xf[t] = xsv;
            float gv = bf2f(pxs[t * 1024 + 512]);
            gv = gv / (1.f + __expf(-gv));
            u16 gb16 = f2bf(gv);
            if (t & 1) gr[t >> 1] |= (unsigned)gb16 << 16;
            else       gr[t >> 1] = gb16;
            a0 = a1; a1 = a2; a2 = a3;
        }
        size_t trow = (size_t)ic * TOK + m0;
        #pragma unroll
        for (int q = 0; q < 4; ++q)
            *(float4*)&xs_T[trow + q * 4] = make_float4(xf[q * 4], xf[q * 4 + 1],
                                                        xf[q * 4 + 2], xf[q * 4 + 3]);
        *(uint4*)&gate_T[trow]     = make_uint4(gr[0], gr[1], gr[2], gr[3]);
        *(uint4*)&gate_T[trow + 8] = make_uint4(gr[4], gr[5], gr[6], gr[7]);
    }
    __syncthreads();

    // ---- MFMA1 partial: K slice [w*64, w*64+64) ----
    {
        f32x4 acc[3] = {};
        const u16* wbase = W + (size_t)r * 512 + w * 64 + g * 8;
        #pragma unroll
        for (int ks = 0; ks < 2; ++ks) {
            bf16x8 af = *(const bf16x8*)&xsL[r][w * 64 + ks * 32 + g * 8];
            #pragma unroll
            for (int fn = 0; fn < 3; ++fn) {
                bf16x8 bfr = *(const bf16x8*)(wbase + (size_t)fn * 16 * 512 + ks * 32);
                acc[fn] = __builtin_amdgcn_mfma_f32_16x16x32_bf16(af, bfr, acc[fn], 0, 0, 0);
            }
        }
        #pragma unroll
        for (int fn = 0; fn < 3; ++fn)
            #pragma unroll
            for (int v = 0; v < 4; ++v)
                sP[w][g * 4 + v][fn * 16 + r] = acc[fn][v];
    }
    __syncthreads();

    // ---- reduce 8 partials (768 outputs over 512 threads) ----
    #pragma unroll
    for (int e = 0; e < 2; ++e) {
        int o = tid + e * 512;
        if (o < 768) {
            int row = o / 48, col = o - row * 48;
            float s = 0.f;
            #pragma unroll
            for (int p = 0; p < 8; ++p) s += sP[p][row][col];
            sT[row][col] = s;
        }
    }
    __syncthreads();

    // ---- bc: grouped float4-friendly layout (one float per thread) ----
    {
        int l = tid;                    // 0..511
        int group = l >> 7;             // 4 tokens per group
        int rem = l & 127;              // bit6=side, bits5..2=n, bits1..0=tl
        int side = rem >> 6;
        int nn = (rem >> 2) & 15;
        int tq = rem & 3;
        bc[(size_t)blockIdx.x * 512 + l] = sT[group * 4 + tq][16 + side * 16 + nn];
    }

    // ---- MFMA2: dtT tile [512][16]; wave w owns i in [w*64, w*64+64) ----
    bf16x8 bv = {};
    if (g < 2) {
        #pragma unroll
        for (int j = 0; j < 8; ++j)
            bv[j] = (short)f2bf(sT[r][g * 8 + j]);
    }
    int mbase = w * 64;
    #pragma unroll
    for (int mf = 0; mf < 4; ++mf) {
        int mrow = mbase + mf * 16;
        bf16x8 av = {};
        if (g < 2) av = *(const bf16x8*)(dtw + (size_t)(mrow + r) * 16 + g * 8);
        f32x4 a2 = __builtin_amdgcn_mfma_f32_16x16x32_bf16(av, bv, f32x4{}, 0, 0, 0);
        float4 b4 = *(const float4*)&dtb[mrow + g * 4];
        #pragma unroll
        for (int v = 0; v < 4; ++v) {
            int i = mrow + g * 4 + v;
            float val = a2[v] + (&b4.x)[v];
            val = fmaxf(val, 0.f) + log1pf(__expf(-fabsf(val)));
            dtT[(size_t)i * TOK + m0 + r] = val;
        }
    }
}

// -------------------- SSM scan: 32 chunks x 32 steps, register-cached phase 3 ----
// xs_T is f32 now (no unpack); phase 3 affine correction from registers.
__global__ __launch_bounds__(512) void scan_kernel(const float* __restrict__ dt_T,
                                                   const float* __restrict__ xs_T,
                                                   const u16* __restrict__ gate_T,
                                                   const float* __restrict__ bc,
                                                   const float* __restrict__ A_log,
                                                   const float* __restrict__ Dw,
                                                   u16* __restrict__ yb) {
    const int NC = 32;   // chunks of 32 steps
    int n = threadIdx.x & 15;
    int c = threadIdx.x >> 4;          // 0..31

    int lin = (blockIdx.x & 7) * 256 + (blockIdx.x >> 3);   // XCD swizzle
    int b = lin >> 9;
    int i = lin & (IDIM - 1);

    float A = -__expf(A_log[i * NST + n]);

    __shared__ float aprodS[NC][17];
    __shared__ float stendS[NC][17];
    __shared__ float incS[NC][17];

    int t0 = c * 32;
    size_t coff = (size_t)i * TOK + b * LSEQ + t0;
    const float4* dtp = (const float4*)(dt_T + coff);
    const float4* xsp = (const float4*)(xs_T + coff);
    const float*  xg  = xs_T + coff;      // flush reload (per-lane f32)
    const u16*    gg  = gate_T + coff;
    const float4* bp  = (const float4*)(bc + (size_t)(b * LSEQ + t0) * 32);

    // ---- phase 1: cache dA and st0 per step in registers ----
    float dA_r[32], st0_r[32];
    float aprod = 1.f, st = 0.f;
    #pragma unroll
    for (int q = 0; q < 8; ++q) {
        float4 d4 = dtp[q];
        float4 X4 = xsp[q];
        float4 B4 = __builtin_bit_cast(float4, bp[q * 32 + n]);
        #pragma unroll
        for (int j = 0; j < 4; ++j) {
            float dtv = (&d4.x)[j];
            float dA  = __expf(dtv * A);
            dA_r[q * 4 + j] = dA;
            aprod *= dA;
            st = fmaf(dA, st, dtv * (&X4.x)[j] * (&B4.x)[j]);
            st0_r[q * 4 + j] = st;
        }
    }
    aprodS[c][n] = aprod;
    stendS[c][n] = st;
    __syncthreads();

    // ---- phase 2: serial chunk-carry (16 threads over 32 chunks) ----
    if (threadIdx.x < 16) {
        int nn = threadIdx.x;
        float carry = 0.f;
        for (int cc = 0; cc < NC; ++cc) {
            incS[cc][nn] = carry;
            carry = fmaf(aprodS[cc][nn], carry, stendS[cc][nn]);
        }
    }
    __syncthreads();

    // ---- phase 3: affine correction from registers; only C-stream loads ----
    float inc = incS[c][n];
    float cumA = 1.f;
    float Dv = Dw[i];
    u16* y_b = yb + ((size_t)b * LSEQ + t0) * IDIM + i;
    float yacc = 0.f;

    #pragma unroll
    for (int q = 0; q < 8; ++q) {
        float4 C4 = __builtin_bit_cast(float4, bp[q * 32 + 16 + n]);
        #pragma unroll
        for (int j = 0; j < 4; ++j) {
            cumA *= dA_r[q * 4 + j];
            float stv = fmaf(cumA, inc, st0_r[q * 4 + j]);
            float py = stv * (&C4.x)[j];
            DPP_ROW_ADD(py, 0xB1);   // xor 1
            DPP_ROW_ADD(py, 0x4E);   // xor 2
            DPP_ROW_ADD(py, 0x141);  // ^7
            DPP_ROW_ADD(py, 0x140);  // ^15
            yacc = (((q & 3) * 4 + j) == n) ? py : yacc;   // const-vs-n select
        }
        if ((q & 3) == 3) {
            int base = (q - 3) * 4;                 // start of this 16-step group
            float xvn = xg[base + n];               // coalesced 16x f32
            float gvn = bf2f(gg[base + n]);
            float yv = fmaf(xvn, Dv, yacc) * gvn;
            y_b[(size_t)(base + n) * IDIM] = f2bf(yv);
        }
    }
}

// -------------------- final norm (pooled rows only) + MLP head --------------------
__global__ __launch_bounds__(256) void head_kernel(const float* __restrict__ h,
                                                   const int* __restrict__ lengths,
                                                   const float* __restrict__ fw,
                                                   const float* __restrict__ w1,
                                                   const float* __restrict__ b1,
                                                   const float* __restrict__ w2,
                                                   const float* __restrict__ b2,
                                                   float* __restrict__ out) {
    int b = blockIdx.x;
    int c = threadIdx.x;
    int len = lengths[b];
    const float* row = h + ((size_t)b * LSEQ + (len - 1)) * HDIM;
    float v = row[c];
    float s = v * v;
    #pragma unroll
    for (int m = 32; m >= 1; m >>= 1) s += __shfl_xor(s, m, 64);
    __shared__ float ls[4];
    __shared__ float pooled[HDIM];
    __shared__ float hd[64];
    if ((c & 63) == 0) ls[c >> 6] = s;
    __syncthreads();
    float tot = ls[0] + ls[1] + ls[2] + ls[3];
    float rstd = rsqrtf(tot * (1.0f / HDIM) + 1e-5f);
    pooled[c] = v * rstd * fw[c];
    __syncthreads();
    if (c < 64) {
        float a = b1[c];
        for (int k = 0; k < HDIM; ++k) a = fmaf(pooled[k], w1[c * HDIM + k], a);
        float g = 0.5f * a * (1.f + erff(a * 0.70710678118654752f));
        hd[c] = g * w2[c];
    }
    __syncthreads();
    if (c == 0) {
        float o = b2[0];
        for (int k = 0; k < 64; ++k) o += hd[k];
        out[b] = o;
    }
}

extern "C" void kernel_launch(void* const* d_in, const int* in_sizes, int n_in,
                              void* d_out, int out_size, void* d_ws, size_t ws_size,
                              hipStream_t stream) {
    const int*   ids         = (const int*)d_in[0];
    const int*   lengths     = (const int*)d_in[1];
    const float* embed       = (const float*)d_in[2];
    const float* norm_w      = (const float*)d_in[3];
    const float* in_proj_w   = (const float*)d_in[4];
    const float* conv_w      = (const float*)d_in[5];
    const float* conv_b      = (const float*)d_in[6];
    const float* x_proj_w    = (const float*)d_in[7];
    const float* dt_proj_w   = (const float*)d_in[8];
    const float* dt_proj_b   = (const float*)d_in[9];
    const float* A_log       = (const float*)d_in[10];
    const float* Dw          = (const float*)d_in[11];
    const float* out_proj_w  = (const float*)d_in[12];
    const float* final_norm_w= (const float*)d_in[13];
    const float* head_w1     = (const float*)d_in[14];
    const float* head_b1     = (const float*)d_in[15];
    const float* head_w2     = (const float*)d_in[16];
    const float* head_b2     = (const float*)d_in[17];

    float* ws   = (float*)d_ws;
    float* h    = ws;                        // 1,048,576 f32
    float* dtT  = h    + 1048576;            // 2,097,152 f32 (dt_T [512][4096])
    float* bc   = dtT  + 2097152;            //   131,072 f32 (grouped B/C)
    float* xsTf = bc   + 131072;             // 2,097,152 f32 (xs channel-major, f32)
    u16* xb   = (u16*)(xsTf + 2097152);      // 1,048,576 bf16
    u16* yb   = xb   + 1048576;              // 2,097,152 bf16
    u16* wib  = yb   + 2097152;              // 1,048,576 bf16 (in_proj_w)
    u16* wob  = wib  + 1048576;              //   524,288 bf16 (out_proj_w)
    u16* xwb  = wob  + 524288;               //    98,304 bf16 (x_proj_w)
    u16* dtwb = xwb  + 98304;                //    32,768 bf16 (dt_proj_w)
    u16* projb= dtwb + 32768;                // 4,194,304 bf16 ([tok][1024])
    u16* gT   = projb+ 4194304;              // 2,097,152 bf16 ([i][tok])

    embed_kernel<<<TOK * HDIM / 256, 256, 0, stream>>>(ids, embed, h);
    cvt4_bf16_kernel<<<1664, 256, 0, stream>>>(in_proj_w, wib, out_proj_w, wob,
                                               x_proj_w, xwb, dt_proj_w, dtwb);
    rmsnorm_kernel<<<TOK / 4, 256, 0, stream>>>(h, norm_w, xb);   // layer 0

    for (int l = 0; l < LAYERS; ++l) {
        gemm_bf16_kernel<<<dim3(1024 / 128, TOK / 128), 256, 0, stream>>>(
            xb, wib + (size_t)l * 2 * IDIM * HDIM, projb, TOK, 2 * IDIM, HDIM);
        xproj_kernel<<<TOK / 16, 512, 0, stream>>>(
            projb, conv_w + l * IDIM * KCONV, conv_b + l * IDIM,
            xwb + (size_t)l * 48 * IDIM, dtwb + (size_t)l * IDIM * 16,
            dt_proj_b + l * IDIM, bc, dtT, xsTf, gT);
        scan_kernel<<<BATCH * IDIM, 512, 0, stream>>>(
            dtT, xsTf, gT, bc, A_log + (size_t)l * IDIM * NST, Dw + l * IDIM, yb);
        const float* nw_next = (l + 1 < LAYERS) ? (norm_w + (l + 1) * HDIM) : final_norm_w;
        outproj_norm_kernel<<<TOK / 16, 512, 0, stream>>>(
            yb, wob + (size_t)l * HDIM * IDIM, nw_next, h, xb);
    }

    head_kernel<<<BATCH, 256, 0, stream>>>(h, lengths, final_norm_w,
                                           head_w1, head_b1, head_w2, head_b2,
                                           (float*)d_out);
}

// Round 22
// 288.538 us; speedup vs baseline: 1.0527x; 1.0527x over previous
//
#include <hip/hip_runtime.h>
#include <hip/hip_bf16.h>

#define HDIM 256
#define IDIM 512
#define NST 16
#define KCONV 4
#define LAYERS 4
#define BATCH 4
#define LSEQ 1024
#define TOK (BATCH * LSEQ)   // 4096

typedef unsigned short u16;
typedef float f32x4 __attribute__((ext_vector_type(4)));
typedef short bf16x8 __attribute__((ext_vector_type(8)));

static __device__ __forceinline__ u16 f2bf(float f) {
    __hip_bfloat16 h = __float2bfloat16(f);
    return reinterpret_cast<u16&>(h);
}
static __device__ __forceinline__ float bf2f(u16 b) {
    return __builtin_bit_cast(float, (unsigned)b << 16);
}
// unpack bf16 #j (j=0..3) from a uint2 holding 4 packed bf16 (j compile-time)
static __device__ __forceinline__ float bfup(uint2 u, int j) {
    unsigned w = (j < 2) ? u.x : u.y;
    unsigned bits = (j & 1) ? (w & 0xffff0000u) : (w << 16);
    return __builtin_bit_cast(float, bits);
}

// DPP butterfly add over each 16-lane row (all lanes end with the row sum).
#define DPP_ROW_ADD(p, CTRL)                                                   \
    p += __builtin_bit_cast(float, __builtin_amdgcn_update_dpp(                \
             0, __builtin_bit_cast(int, p), CTRL, 0xf, 0xf, false))

// -------------------- embedding --------------------
__global__ __launch_bounds__(256) void embed_kernel(const int* __restrict__ ids,
                                                    const float* __restrict__ embed,
                                                    float* __restrict__ h) {
    int idx = blockIdx.x * 256 + threadIdx.x;
    if (idx < TOK * HDIM) {
        int tok = idx >> 8;
        int c = idx & (HDIM - 1);
        h[idx] = embed[ids[tok] * HDIM + c];
    }
}

// -------------------- f32 -> bf16 bulk convert, 4 weight arrays in one launch ------
__global__ __launch_bounds__(256) void cvt4_bf16_kernel(const float* __restrict__ s0, u16* __restrict__ d0,
                                                        const float* __restrict__ s1, u16* __restrict__ d1,
                                                        const float* __restrict__ s2, u16* __restrict__ d2,
                                                        const float* __restrict__ s3, u16* __restrict__ d3) {
    const float* in;
    u16* out;
    int base;
    int bid = blockIdx.x;
    if (bid < 1024)      { in = s0; out = d0; base = bid; }
    else if (bid < 1536) { in = s1; out = d1; base = bid - 1024; }
    else if (bid < 1632) { in = s2; out = d2; base = bid - 1536; }
    else                 { in = s3; out = d3; base = bid - 1632; }
    int j = (base * 256 + threadIdx.x) * 4;
    float4 v = *(const float4*)&in[j];
    unsigned lo = (unsigned)f2bf(v.x) | ((unsigned)f2bf(v.y) << 16);
    unsigned hi = (unsigned)f2bf(v.z) | ((unsigned)f2bf(v.w) << 16);
    *(uint2*)&out[j] = make_uint2(lo, hi);
}

// -------------------- rmsnorm (layer 0 only): one wave per token ----------------
__global__ __launch_bounds__(256) void rmsnorm_kernel(const float* __restrict__ h,
                                                      const float* __restrict__ w,
                                                      u16* __restrict__ xb) {
    int wid = threadIdx.x >> 6, lane = threadIdx.x & 63;
    int tok = blockIdx.x * 4 + wid;
    float4 v = *(const float4*)&h[(size_t)tok * HDIM + lane * 4];
    float s = v.x * v.x + v.y * v.y + v.z * v.z + v.w * v.w;
    #pragma unroll
    for (int m = 32; m >= 1; m >>= 1) s += __shfl_xor(s, m, 64);
    float rstd = rsqrtf(s * (1.0f / HDIM) + 1e-5f);
    float4 wv = *(const float4*)&w[lane * 4];
    unsigned lo = (unsigned)f2bf(v.x * rstd * wv.x) | ((unsigned)f2bf(v.y * rstd * wv.y) << 16);
    unsigned hi = (unsigned)f2bf(v.z * rstd * wv.z) | ((unsigned)f2bf(v.w * rstd * wv.w) << 16);
    *(uint2*)&xb[(size_t)tok * HDIM + lane * 4] = make_uint2(lo, hi);
}

// -------------------- bf16 MFMA GEMM 128x128 (in_proj): C = A @ W^T, bf16 out ----
__global__ __launch_bounds__(256) void gemm_bf16_kernel(const u16* __restrict__ A,
                                                        const u16* __restrict__ W,
                                                        u16* __restrict__ C,
                                                        int M, int N, int K) {
    const int BM = 128, BK = 32;
    __shared__ __align__(16) u16 Al[BM][BK + 8];
    __shared__ __align__(16) u16 Bl[BM][BK + 8];
    int m0 = blockIdx.y * BM, n0 = blockIdx.x * BM;
    int tid = threadIdx.x;
    int lane = tid & 63;
    int wid = tid >> 6;
    int wr = wid >> 1, wc = wid & 1;
    int r = lane & 15, g = lane >> 4;

    f32x4 acc[4][4] = {};

    int srow = tid & 127;
    const u16* src = (tid < 128) ? (A + (size_t)(m0 + srow) * K)
                                 : (W + (size_t)(n0 + srow) * K);
    u16* dstrow = (tid < 128) ? &Al[srow][0] : &Bl[srow][0];

    for (int k0 = 0; k0 < K; k0 += BK) {
        uint4 v0 = *(const uint4*)(src + k0);
        uint4 v1 = *(const uint4*)(src + k0 + 8);
        uint4 v2 = *(const uint4*)(src + k0 + 16);
        uint4 v3 = *(const uint4*)(src + k0 + 24);
        __syncthreads();
        *(uint4*)(dstrow)      = v0;
        *(uint4*)(dstrow + 8)  = v1;
        *(uint4*)(dstrow + 16) = v2;
        *(uint4*)(dstrow + 24) = v3;
        __syncthreads();

        bf16x8 af[4], bfr[4];
        #pragma unroll
        for (int f = 0; f < 4; ++f) {
            af[f]  = *(const bf16x8*)&Al[wr * 64 + f * 16 + r][g * 8];
            bfr[f] = *(const bf16x8*)&Bl[wc * 64 + f * 16 + r][g * 8];
        }
        #pragma unroll
        for (int fm = 0; fm < 4; ++fm)
            #pragma unroll
            for (int fn = 0; fn < 4; ++fn)
                acc[fm][fn] = __builtin_amdgcn_mfma_f32_16x16x32_bf16(
                    af[fm], bfr[fn], acc[fm][fn], 0, 0, 0);
    }

    #pragma unroll
    for (int fm = 0; fm < 4; ++fm) {
        #pragma unroll
        for (int fn = 0; fn < 4; ++fn) {
            int col = n0 + wc * 64 + fn * 16 + r;
            #pragma unroll
            for (int v = 0; v < 4; ++v) {
                int row = m0 + wr * 64 + fm * 16 + g * 4 + v;
                C[(size_t)row * N + col] = f2bf(acc[fm][fn][v]);
            }
        }
    }
}

// -------------------- out_proj + residual + next-layer rmsnorm fused --------------
__global__ __launch_bounds__(256) void outproj_norm_kernel(const u16* __restrict__ Y,   // yb [TOK][512]
                                                           const u16* __restrict__ W,   // wob [256][512]
                                                           const float* __restrict__ nw,// next norm_w [256]
                                                           float* __restrict__ h,
                                                           u16* __restrict__ xb) {
    __shared__ float sH[16][260];
    int m0 = blockIdx.x * 16;
    int tid = threadIdx.x;
    int lane = tid & 63;
    int w = tid >> 6;
    int r = lane & 15, g = lane >> 4;

    f32x4 acc[4] = {};
    const u16* yrow  = Y + (size_t)(m0 + r) * 512 + g * 8;
    const u16* wbase = W + (size_t)(w * 64 + r) * 512 + g * 8;
    #pragma unroll
    for (int k0 = 0; k0 < 512; k0 += 32) {
        bf16x8 af = *(const bf16x8*)(yrow + k0);
        #pragma unroll
        for (int fn = 0; fn < 4; ++fn) {
            bf16x8 bfr = *(const bf16x8*)(wbase + (size_t)fn * 16 * 512 + k0);
            acc[fn] = __builtin_amdgcn_mfma_f32_16x16x32_bf16(af, bfr, acc[fn], 0, 0, 0);
        }
    }

    #pragma unroll
    for (int fn = 0; fn < 4; ++fn) {
        int col = w * 64 + fn * 16 + r;
        #pragma unroll
        for (int v = 0; v < 4; ++v) {
            int row = g * 4 + v;
            size_t off = (size_t)(m0 + row) * HDIM + col;
            float hv = h[off] + acc[fn][v];
            h[off] = hv;
            sH[row][col] = hv;
        }
    }
    __syncthreads();

    int row = tid >> 4, part = tid & 15;
    const float* sr = &sH[row][part * 16];
    float s = 0.f;
    #pragma unroll
    for (int j = 0; j < 16; ++j) s = fmaf(sr[j], sr[j], s);
    DPP_ROW_ADD(s, 0xB1);
    DPP_ROW_ADD(s, 0x4E);
    DPP_ROW_ADD(s, 0x141);
    DPP_ROW_ADD(s, 0x140);
    float rstd = rsqrtf(s * (1.0f / HDIM) + 1e-5f);
    const float* nwp = &nw[part * 16];
    unsigned pk[8];
    #pragma unroll
    for (int j = 0; j < 8; ++j) {
        u16 lo = f2bf(sr[2 * j]     * rstd * nwp[2 * j]);
        u16 hi = f2bf(sr[2 * j + 1] * rstd * nwp[2 * j + 1]);
        pk[j] = (unsigned)lo | ((unsigned)hi << 16);
    }
    u16* dst = xb + (size_t)(m0 + row) * HDIM + part * 16;
    *(uint4*)(dst)     = make_uint4(pk[0], pk[1], pk[2], pk[3]);
    *(uint4*)(dst + 8) = make_uint4(pk[4], pk[5], pk[6], pk[7]);
}

// -------------------- conv + x_proj + dt_proj fused --------------------
__global__ __launch_bounds__(512) void xproj_kernel(const u16* __restrict__ proj,  // [TOK][1024]
                                                    const float* __restrict__ cw,
                                                    const float* __restrict__ cb,
                                                    const u16* __restrict__ W,     // xwb [48][512]
                                                    const u16* __restrict__ dtw,   // [512][16]
                                                    const float* __restrict__ dtb, // [512]
                                                    float* __restrict__ bc,
                                                    float* __restrict__ dtT,
                                                    u16* __restrict__ xs_T,
                                                    u16* __restrict__ gate_T) {
    __shared__ __align__(16) u16 xsL[16][520];
    __shared__ float sP[8][16][52];
    __shared__ float sT[16][52];
    int m0 = blockIdx.x * 16;
    int tid = threadIdx.x;
    int lane = tid & 63;
    int w = tid >> 6;                  // wave id
    int r = lane & 15, g = lane >> 4;
    int tl = m0 & (LSEQ - 1);          // seq-local base (block-uniform)

    // ---- conv + silu, channel ic = tid ----
    {
        int ic = tid;
        const u16* pxs = proj + (size_t)m0 * 1024 + ic;
        float4 wq = *(const float4*)&cw[ic * 4];
        float bias = cb[ic];
        float a0 = (tl >= 3) ? bf2f(pxs[-3 * 1024]) : 0.f;
        float a1 = (tl >= 2) ? bf2f(pxs[-2 * 1024]) : 0.f;
        float a2 = (tl >= 1) ? bf2f(pxs[-1 * 1024]) : 0.f;
        unsigned xr[8], gr[8];
        #pragma unroll
        for (int t = 0; t < 16; ++t) {
            float a3 = bf2f(pxs[t * 1024]);
            float acc = bias;
            acc = fmaf(a0, wq.x, acc);
            acc = fmaf(a1, wq.y, acc);
            acc = fmaf(a2, wq.z, acc);
            acc = fmaf(a3, wq.w, acc);
            float xsv = acc / (1.f + __expf(-acc));
            u16 xb16 = f2bf(xsv);
            xsL[t][ic] = xb16;
            float gv = bf2f(pxs[t * 1024 + 512]);
            gv = gv / (1.f + __expf(-gv));
            u16 gb16 = f2bf(gv);
            if (t & 1) { xr[t >> 1] |= (unsigned)xb16 << 16; gr[t >> 1] |= (unsigned)gb16 << 16; }
            else       { xr[t >> 1] = xb16;                   gr[t >> 1] = gb16; }
            a0 = a1; a1 = a2; a2 = a3;
        }
        size_t trow = (size_t)ic * TOK + m0;
        *(uint4*)&xs_T[trow]       = make_uint4(xr[0], xr[1], xr[2], xr[3]);
        *(uint4*)&xs_T[trow + 8]   = make_uint4(xr[4], xr[5], xr[6], xr[7]);
        *(uint4*)&gate_T[trow]     = make_uint4(gr[0], gr[1], gr[2], gr[3]);
        *(uint4*)&gate_T[trow + 8] = make_uint4(gr[4], gr[5], gr[6], gr[7]);
    }
    __syncthreads();

    // ---- MFMA1 partial: K slice [w*64, w*64+64) ----
    {
        f32x4 acc[3] = {};
        const u16* wbase = W + (size_t)r * 512 + w * 64 + g * 8;
        #pragma unroll
        for (int ks = 0; ks < 2; ++ks) {
            bf16x8 af = *(const bf16x8*)&xsL[r][w * 64 + ks * 32 + g * 8];
            #pragma unroll
            for (int fn = 0; fn < 3; ++fn) {
                bf16x8 bfr = *(const bf16x8*)(wbase + (size_t)fn * 16 * 512 + ks * 32);
                acc[fn] = __builtin_amdgcn_mfma_f32_16x16x32_bf16(af, bfr, acc[fn], 0, 0, 0);
            }
        }
        #pragma unroll
        for (int fn = 0; fn < 3; ++fn)
            #pragma unroll
            for (int v = 0; v < 4; ++v)
                sP[w][g * 4 + v][fn * 16 + r] = acc[fn][v];
    }
    __syncthreads();

    // ---- reduce 8 partials (768 outputs over 512 threads) ----
    #pragma unroll
    for (int e = 0; e < 2; ++e) {
        int o = tid + e * 512;
        if (o < 768) {
            int row = o / 48, col = o - row * 48;
            float s = 0.f;
            #pragma unroll
            for (int p = 0; p < 8; ++p) s += sP[p][row][col];
            sT[row][col] = s;
        }
    }
    __syncthreads();

    // ---- bc: grouped float4-friendly layout (one float per thread) ----
    {
        int l = tid;                    // 0..511
        int group = l >> 7;             // 4 tokens per group
        int rem = l & 127;              // bit6=side, bits5..2=n, bits1..0=tl
        int side = rem >> 6;
        int nn = (rem >> 2) & 15;
        int tq = rem & 3;
        bc[(size_t)blockIdx.x * 512 + l] = sT[group * 4 + tq][16 + side * 16 + nn];
    }

    // ---- MFMA2: dtT tile [512][16]; wave w owns i in [w*64, w*64+64) ----
    bf16x8 bv = {};
    if (g < 2) {
        #pragma unroll
        for (int j = 0; j < 8; ++j)
            bv[j] = (short)f2bf(sT[r][g * 8 + j]);
    }
    int mbase = w * 64;
    #pragma unroll
    for (int mf = 0; mf < 4; ++mf) {
        int mrow = mbase + mf * 16;
        bf16x8 av = {};
        if (g < 2) av = *(const bf16x8*)(dtw + (size_t)(mrow + r) * 16 + g * 8);
        f32x4 a2 = __builtin_amdgcn_mfma_f32_16x16x32_bf16(av, bv, f32x4{}, 0, 0, 0);
        float4 b4 = *(const float4*)&dtb[mrow + g * 4];
        #pragma unroll
        for (int v = 0; v < 4; ++v) {
            int i = mrow + g * 4 + v;
            float val = a2[v] + (&b4.x)[v];
            val = fmaxf(val, 0.f) + log1pf(__expf(-fabsf(val)));
            dtT[(size_t)i * TOK + m0 + r] = val;
        }
    }
}

// -------------------- SSM scan: 32 chunks x 32 steps, register-cached phase 3 ----
__global__ __launch_bounds__(512) void scan_kernel(const float* __restrict__ dt_T,
                                                   const u16* __restrict__ xs_T,
                                                   const u16* __restrict__ gate_T,
                                                   const float* __restrict__ bc,
                                                   const float* __restrict__ A_log,
                                                   const float* __restrict__ Dw,
                                                   u16* __restrict__ yb) {
    const int NC = 32;   // chunks of 32 steps
    int n = threadIdx.x & 15;
    int c = threadIdx.x >> 4;          // 0..31

    int lin = (blockIdx.x & 7) * 256 + (blockIdx.x >> 3);   // XCD swizzle
    int b = lin >> 9;
    int i = lin & (IDIM - 1);

    float A = -__expf(A_log[i * NST + n]);

    __shared__ float aprodS[NC][17];
    __shared__ float stendS[NC][17];
    __shared__ float incS[NC][17];

    int t0 = c * 32;
    size_t coff = (size_t)i * TOK + b * LSEQ + t0;
    const float4* dtp = (const float4*)(dt_T + coff);
    const uint2*  xsp = (const uint2*)(xs_T + coff);
    const u16*    xg  = xs_T + coff;      // flush reload (per-lane u16)
    const u16*    gg  = gate_T + coff;
    const float4* bp  = (const float4*)(bc + (size_t)(b * LSEQ + t0) * 32);

    // ---- phase 1: cache dA and st0 per step in registers ----
    float dA_r[32], st0_r[32];
    float aprod = 1.f, st = 0.f;
    #pragma unroll
    for (int q = 0; q < 8; ++q) {
        float4 d4 = dtp[q];
        uint2  xu = xsp[q];
        float4 B4 = __builtin_bit_cast(float4, bp[q * 32 + n]);
        #pragma unroll
        for (int j = 0; j < 4; ++j) {
            float dtv = (&d4.x)[j];
            float dA  = __expf(dtv * A);
            dA_r[q * 4 + j] = dA;
            aprod *= dA;
            st = fmaf(dA, st, dtv * bfup(xu, j) * (&B4.x)[j]);
            st0_r[q * 4 + j] = st;
        }
    }
    aprodS[c][n] = aprod;
    stendS[c][n] = st;
    __syncthreads();

    // ---- phase 2: serial chunk-carry (16 threads over 32 chunks) ----
    if (threadIdx.x < 16) {
        int nn = threadIdx.x;
        float carry = 0.f;
        for (int cc = 0; cc < NC; ++cc) {
            incS[cc][nn] = carry;
            carry = fmaf(aprodS[cc][nn], carry, stendS[cc][nn]);
        }
    }
    __syncthreads();

    // ---- phase 3: affine correction from registers; only C-stream loads ----
    float inc = incS[c][n];
    float cumA = 1.f;
    float Dv = Dw[i];
    u16* y_b = yb + ((size_t)b * LSEQ + t0) * IDIM + i;
    float yacc = 0.f;

    #pragma unroll
    for (int q = 0; q < 8; ++q) {
        float4 C4 = __builtin_bit_cast(float4, bp[q * 32 + 16 + n]);
        #pragma unroll
        for (int j = 0; j < 4; ++j) {
            cumA *= dA_r[q * 4 + j];
            float stv = fmaf(cumA, inc, st0_r[q * 4 + j]);
            float py = stv * (&C4.x)[j];
            DPP_ROW_ADD(py, 0xB1);   // xor 1
            DPP_ROW_ADD(py, 0x4E);   // xor 2
            DPP_ROW_ADD(py, 0x141);  // ^7
            DPP_ROW_ADD(py, 0x140);  // ^15
            yacc = (((q & 3) * 4 + j) == n) ? py : yacc;   // const-vs-n select
        }
        if ((q & 3) == 3) {
            int base = (q - 3) * 4;                 // start of this 16-step group
            float xvn = bf2f(xg[base + n]);         // coalesced 16x u16
            float gvn = bf2f(gg[base + n]);
            float yv = fmaf(xvn, Dv, yacc) * gvn;
            y_b[(size_t)(base + n) * IDIM] = f2bf(yv);
        }
    }
}

// -------------------- final norm (pooled rows only) + MLP head --------------------
__global__ __launch_bounds__(256) void head_kernel(const float* __restrict__ h,
                                                   const int* __restrict__ lengths,
                                                   const float* __restrict__ fw,
                                                   const float* __restrict__ w1,
                                                   const float* __restrict__ b1,
                                                   const float* __restrict__ w2,
                                                   const float* __restrict__ b2,
                                                   float* __restrict__ out) {
    int b = blockIdx.x;
    int c = threadIdx.x;
    int len = lengths[b];
    const float* row = h + ((size_t)b * LSEQ + (len - 1)) * HDIM;
    float v = row[c];
    float s = v * v;
    #pragma unroll
    for (int m = 32; m >= 1; m >>= 1) s += __shfl_xor(s, m, 64);
    __shared__ float ls[4];
    __shared__ float pooled[HDIM];
    __shared__ float hd[64];
    if ((c & 63) == 0) ls[c >> 6] = s;
    __syncthreads();
    float tot = ls[0] + ls[1] + ls[2] + ls[3];
    float rstd = rsqrtf(tot * (1.0f / HDIM) + 1e-5f);
    pooled[c] = v * rstd * fw[c];
    __syncthreads();
    if (c < 64) {
        float a = b1[c];
        for (int k = 0; k < HDIM; ++k) a = fmaf(pooled[k], w1[c * HDIM + k], a);
        float g = 0.5f * a * (1.f + erff(a * 0.70710678118654752f));
        hd[c] = g * w2[c];
    }
    __syncthreads();
    if (c == 0) {
        float o = b2[0];
        for (int k = 0; k < 64; ++k) o += hd[k];
        out[b] = o;
    }
}

extern "C" void kernel_launch(void* const* d_in, const int* in_sizes, int n_in,
                              void* d_out, int out_size, void* d_ws, size_t ws_size,
                              hipStream_t stream) {
    const int*   ids         = (const int*)d_in[0];
    const int*   lengths     = (const int*)d_in[1];
    const float* embed       = (const float*)d_in[2];
    const float* norm_w      = (const float*)d_in[3];
    const float* in_proj_w   = (const float*)d_in[4];
    const float* conv_w      = (const float*)d_in[5];
    const float* conv_b      = (const float*)d_in[6];
    const float* x_proj_w    = (const float*)d_in[7];
    const float* dt_proj_w   = (const float*)d_in[8];
    const float* dt_proj_b   = (const float*)d_in[9];
    const float* A_log       = (const float*)d_in[10];
    const float* Dw          = (const float*)d_in[11];
    const float* out_proj_w  = (const float*)d_in[12];
    const float* final_norm_w= (const float*)d_in[13];
    const float* head_w1     = (const float*)d_in[14];
    const float* head_b1     = (const float*)d_in[15];
    const float* head_w2     = (const float*)d_in[16];
    const float* head_b2     = (const float*)d_in[17];

    float* ws   = (float*)d_ws;
    float* h    = ws;                        // 1,048,576 f32
    float* dtT  = h    + 1048576;            // 2,097,152 f32 (dt_T [512][4096])
    float* bc   = dtT  + 2097152;            //   131,072 f32 (grouped B/C)
    u16* xb   = (u16*)(bc + 131072);         // 1,048,576 bf16
    u16* yb   = xb   + 1048576;              // 2,097,152 bf16
    u16* wib  = yb   + 2097152;              // 1,048,576 bf16 (in_proj_w)
    u16* wob  = wib  + 1048576;              //   524,288 bf16 (out_proj_w)
    u16* xwb  = wob  + 524288;               //    98,304 bf16 (x_proj_w)
    u16* dtwb = xwb  + 98304;                //    32,768 bf16 (dt_proj_w)
    u16* projb= dtwb + 32768;                // 4,194,304 bf16 ([tok][1024])
    u16* xsT  = projb+ 4194304;              // 2,097,152 bf16 ([i][tok])
    u16* gT   = xsT  + 2097152;              // 2,097,152 bf16 ([i][tok])

    embed_kernel<<<TOK * HDIM / 256, 256, 0, stream>>>(ids, embed, h);
    cvt4_bf16_kernel<<<1664, 256, 0, stream>>>(in_proj_w, wib, out_proj_w, wob,
                                               x_proj_w, xwb, dt_proj_w, dtwb);
    rmsnorm_kernel<<<TOK / 4, 256, 0, stream>>>(h, norm_w, xb);   // layer 0

    for (int l = 0; l < LAYERS; ++l) {
        gemm_bf16_kernel<<<dim3(1024 / 128, TOK / 128), 256, 0, stream>>>(
            xb, wib + (size_t)l * 2 * IDIM * HDIM, projb, TOK, 2 * IDIM, HDIM);
        xproj_kernel<<<TOK / 16, 512, 0, stream>>>(
            projb, conv_w + l * IDIM * KCONV, conv_b + l * IDIM,
            xwb + (size_t)l * 48 * IDIM, dtwb + (size_t)l * IDIM * 16,
            dt_proj_b + l * IDIM, bc, dtT, xsT, gT);
        scan_kernel<<<BATCH * IDIM, 512, 0, stream>>>(
            dtT, xsT, gT, bc, A_log + (size_t)l * IDIM * NST, Dw + l * IDIM, yb);
        const float* nw_next = (l + 1 < LAYERS) ? (norm_w + (l + 1) * HDIM) : final_norm_w;
        outproj_norm_kernel<<<TOK / 16, 256, 0, stream>>>(
            yb, wob + (size_t)l * HDIM * IDIM, nw_next, h, xb);
    }

    head_kernel<<<BATCH, 256, 0, stream>>>(h, lengths, final_norm_w,
                                           head_w1, head_b1, head_w2, head_b2,
                                           (float*)d_out);
}